// Round 11
// baseline (184.100 us; speedup 1.0000x reference)
//
#include <hip/hip_runtime.h>
#include <cmath>

#pragma clang fp contract(off)

// Monolithic hybrid, ILP-2: each thread solves TWO independent instances
// (tid and tid+TOTAL/2) with their Gram-Jacobi chains interleaved in one
// loop nest. r10 counters showed the Gram fast path is latency-bound
// (VALUBusy 67%, serial zeta->rcp->sqrt->t->M' chain); a second independent
// chain fills the stalls. Rotations are branchless (select t->0 below
// threshold) for straight-line scheduling. est model (squared-spectrum,
// cutoff 1000) and the sgesdd-f32 slow path are byte-identical to r10/r4
// (passed, absmax 1.2e4 vs threshold 1.9e4).

constexpr int BATCH  = 65536;
constexpr int VIEWS  = 4;
constexpr int JOINTS = 17;
constexpr int TOTAL  = BATCH * JOINTS;   // 1,114,112
constexpr int HALF   = TOTAL / 2;        // 557,056 = 2176 * 256 exactly

#define EPS32  5.9604645e-08f   /* slamch('E') = 2^-24 */
#define UNFL32 1.17549435e-38f  /* slamch('S') */

__device__ __forceinline__ float fsign(float a, float b) { return copysignf(a, b); }

// fast 1-ulp hardware ops — fast path only
__device__ __forceinline__ float frcp(float x)  { return __builtin_amdgcn_rcpf(x); }
__device__ __forceinline__ float frsq(float x)  { return __builtin_amdgcn_rsqf(x); }
__device__ __forceinline__ float fsqrtf(float x){ return __builtin_amdgcn_sqrtf(x); }

// ===================== slow path (bit-identical to round 4) =====================

__device__ float snrm2_(const float* x, int n) {
    double s = 0.0;
    for (int i = 0; i < n; ++i) { double xi = (double)x[i]; s += xi * xi; }
    return (float)sqrt(s);
}

__device__ float slapy2_(float x, float y) {
    float xa = fabsf(x), ya = fabsf(y);
    float w = fmaxf(xa, ya), z = fminf(xa, ya);
    if (z == 0.0f) return w;
    float q = z / w;
    return w * __fsqrt_rn(1.0f + q * q);
}

__device__ float slarfg_(int n, float& alpha, float* x) {
    if (n <= 1) return 0.0f;
    float xnorm = snrm2_(x, n - 1);
    if (xnorm == 0.0f) return 0.0f;
    float beta = -fsign(slapy2_(alpha, xnorm), alpha);
    float tau  = (beta - alpha) / beta;
    float scal = 1.0f / (alpha - beta);
    for (int i = 0; i < n - 1; ++i) x[i] = scal * x[i];
    alpha = beta;
    return tau;
}

__device__ void slartg_(float f, float g, float& c, float& s, float& r) {
    if (g == 0.0f)      { c = 1.0f; s = 0.0f; r = f; }
    else if (f == 0.0f) { c = 0.0f; s = fsign(1.0f, g); r = fabsf(g); }
    else {
        float f1 = fabsf(f);
        float dd = __fsqrt_rn(f * f + g * g);
        c = f1 / dd;
        r = fsign(dd, f);
        s = g / r;
    }
}

__device__ void slas2_(float f, float g, float h, float& ssmin, float& ssmax) {
    float fa = fabsf(f), ga = fabsf(g), ha = fabsf(h);
    float fhmn = fminf(fa, ha), fhmx = fmaxf(fa, ha);
    if (fhmn == 0.0f) {
        ssmin = 0.0f;
        if (fhmx == 0.0f) ssmax = ga;
        else {
            float mn = fminf(fhmx, ga), mx = fmaxf(fhmx, ga);
            float q = mn / mx;
            ssmax = mx * __fsqrt_rn(1.0f + q * q);
        }
    } else {
        if (ga < fhmx) {
            float as_ = 1.0f + fhmn / fhmx;
            float at_ = (fhmx - fhmn) / fhmx;
            float q = ga / fhmx;
            float au = q * q;
            float cc = 2.0f / (__fsqrt_rn(as_ * as_ + au) + __fsqrt_rn(at_ * at_ + au));
            ssmin = fhmn * cc;
            ssmax = fhmx / cc;
        } else {
            float au = fhmx / ga;
            if (au == 0.0f) { ssmin = (fhmn * fhmx) / ga; ssmax = ga; }
            else {
                float as_ = 1.0f + fhmn / fhmx;
                float at_ = (fhmx - fhmn) / fhmx;
                float t1 = as_ * au, t2 = at_ * au;
                float cc = 1.0f / (__fsqrt_rn(1.0f + t1 * t1) + __fsqrt_rn(1.0f + t2 * t2));
                ssmin = (fhmn * cc) * au;
                ssmin = ssmin + ssmin;
                ssmax = ga / (cc + cc);
            }
        }
    }
}

__device__ void slasv2_(float f, float g, float h,
                        float& ssmin, float& ssmax,
                        float& snr, float& csr, float& snl, float& csl) {
    float ft = f, fa = fabsf(f), ht = h, ha = fabsf(h);
    int pmax = 1;
    bool swap = (ha > fa);
    if (swap) { pmax = 3; float t = ft; ft = ht; ht = t; t = fa; fa = ha; ha = t; }
    float gt = g, ga = fabsf(g);
    float clt = 0.0f, crt = 0.0f, slt = 0.0f, srt = 0.0f;
    if (ga == 0.0f) {
        ssmin = ha; ssmax = fa;
        clt = 1.0f; crt = 1.0f; slt = 0.0f; srt = 0.0f;
    } else {
        bool gasmal = true;
        if (ga > fa) {
            pmax = 2;
            if ((fa / ga) < EPS32) {
                gasmal = false;
                ssmax = ga;
                if (ha > 1.0f) ssmin = fa / (ga / ha);
                else           ssmin = (fa / ga) * ha;
                clt = 1.0f; slt = ht / gt;
                srt = 1.0f; crt = ft / gt;
            }
        }
        if (gasmal) {
            float dd = fa - ha;
            float l_ = (dd == fa) ? 1.0f : (dd / fa);
            float m_ = gt / ft;
            float t_ = 2.0f - l_;
            float mm = m_ * m_, tt = t_ * t_;
            float s_ = __fsqrt_rn(tt + mm);
            float r_ = (l_ == 0.0f) ? fabsf(m_) : __fsqrt_rn(l_ * l_ + mm);
            float a_ = 0.5f * (s_ + r_);
            ssmin = ha / a_;
            ssmax = fa * a_;
            if (mm == 0.0f) {
                if (l_ == 0.0f) t_ = fsign(2.0f, ft) * fsign(1.0f, gt);
                else            t_ = gt / fsign(dd, ft) + m_ / t_;
            } else {
                t_ = (m_ / (s_ + t_) + m_ / (r_ + l_)) * (1.0f + a_);
            }
            float ll = __fsqrt_rn(t_ * t_ + 4.0f);
            crt = 2.0f / ll;
            srt = t_ / ll;
            clt = (crt + srt * m_) / a_;
            slt = (ht / ft) * srt / a_;
        }
    }
    if (swap) { csl = srt; snl = crt; csr = slt; snr = clt; }
    else      { csl = clt; snl = slt; csr = crt; snr = srt; }
    float tsign = 0.0f;
    if (pmax == 1) tsign = fsign(1.0f, csr) * fsign(1.0f, csl) * fsign(1.0f, f);
    if (pmax == 2) tsign = fsign(1.0f, snr) * fsign(1.0f, csl) * fsign(1.0f, g);
    if (pmax == 3) tsign = fsign(1.0f, snr) * fsign(1.0f, snl) * fsign(1.0f, h);
    ssmax = fsign(ssmax, tsign);
    ssmin = fsign(ssmin, tsign * fsign(1.0f, f) * fsign(1.0f, h));
}

__device__ void sbdsqr4_(float* d, float* e, float VT[4][4]) {
    const float eps = EPS32, unfl = UNFL32;
    const float tol = 10.0f * eps;
    float thresh;
    {
        float sminoa = fabsf(d[0]);
        if (sminoa != 0.0f) {
            float mu = sminoa;
            for (int i = 1; i < 4; ++i) {
                mu = fabsf(d[i]) * (mu / (mu + fabsf(e[i - 1])));
                sminoa = fminf(sminoa, mu);
                if (sminoa == 0.0f) break;
            }
        }
        sminoa = sminoa / __fsqrt_rn(4.0f);
        thresh = fmaxf(tol * sminoa, 6.0f * (4.0f * (4.0f * unfl)));
    }
    int M = 4, oldll = -1000, oldm = -1000, idir = 0;
    float sminl = 0.0f;
    float rc[3], rs[3];
    for (int guard = 0; guard < 300 && M > 1; ++guard) {
        float smaxb = fabsf(d[M - 1]);
        int LLs = 0; bool defl = false, split = false;
        for (int lll = 1; lll <= M - 1; ++lll) {
            int ll = M - lll;
            float abse = fabsf(e[ll - 1]);
            float abss = fabsf(d[ll - 1]);
            if (abse <= thresh) {
                e[ll - 1] = 0.0f;
                if (ll == M - 1) { M = M - 1; defl = true; }
                else { LLs = ll; split = true; }
                break;
            }
            smaxb = fmaxf(fmaxf(smaxb, abss), abse);
        }
        if (defl) continue;
        int LL = (split ? LLs : 0) + 1;
        if (LL == M - 1) {
            float sigmn, sigmx, sinr, cosr, sinl, cosl;
            slasv2_(d[M - 2], e[M - 2], d[M - 1], sigmn, sigmx, sinr, cosr, sinl, cosl);
            d[M - 2] = sigmx; e[M - 2] = 0.0f; d[M - 1] = sigmn;
            for (int cc = 0; cc < 4; ++cc) {
                float st = cosr * VT[M - 2][cc] + sinr * VT[M - 1][cc];
                VT[M - 1][cc] = cosr * VT[M - 1][cc] - sinr * VT[M - 2][cc];
                VT[M - 2][cc] = st;
            }
            M -= 2;
            continue;
        }
        if (LL > oldm || M < oldll)
            idir = (fabsf(d[LL - 1]) >= fabsf(d[M - 1])) ? 1 : 2;
        bool cyc = false;
        if (idir == 1) {
            if (fabsf(e[M - 2]) <= tol * fabsf(d[M - 1])) { e[M - 2] = 0.0f; continue; }
            float mu = fabsf(d[LL - 1]); sminl = mu;
            for (int lll = LL; lll <= M - 1; ++lll) {
                if (fabsf(e[lll - 1]) <= tol * mu) { e[lll - 1] = 0.0f; cyc = true; break; }
                mu = fabsf(d[lll]) * (mu / (mu + fabsf(e[lll - 1])));
                sminl = fminf(sminl, mu);
            }
        } else {
            if (fabsf(e[LL - 1]) <= tol * fabsf(d[LL - 1])) { e[LL - 1] = 0.0f; continue; }
            float mu = fabsf(d[M - 1]); sminl = mu;
            for (int lll = M - 1; lll >= LL; --lll) {
                if (fabsf(e[lll - 1]) <= tol * mu) { e[lll - 1] = 0.0f; cyc = true; break; }
                mu = fabsf(d[lll - 1]) * (mu / (mu + fabsf(e[lll - 1])));
                sminl = fminf(sminl, mu);
            }
        }
        if (cyc) continue;
        oldll = LL; oldm = M;
        float shift = 0.0f;
        {
            float lhs = (4.0f * tol) * (sminl / smaxb);
            if (!(lhs <= fmaxf(eps, 0.01f * tol))) {
                float sll, rr2;
                if (idir == 1) { sll = fabsf(d[LL - 1]); slas2_(d[M - 2], e[M - 2], d[M - 1], shift, rr2); }
                else           { sll = fabsf(d[M - 1]); slas2_(d[LL - 1], e[LL - 1], d[LL], shift, rr2); }
                if (sll > 0.0f) {
                    float q = shift / sll;
                    if (q * q < eps) shift = 0.0f;
                }
            }
        }
        if (shift == 0.0f) {
            if (idir == 1) {
                float cs = 1.0f, oldcs = 1.0f, sn = 0.0f, oldsn = 0.0f, rr = 0.0f;
                for (int i = LL; i <= M - 1; ++i) {
                    float fv = d[i - 1] * cs;
                    slartg_(fv, e[i - 1], cs, sn, rr);
                    if (i > LL) e[i - 2] = oldsn * rr;
                    float fv2 = oldcs * rr;
                    float gv2 = d[i] * sn;
                    slartg_(fv2, gv2, oldcs, oldsn, d[i - 1]);
                    rc[i - LL] = cs; rs[i - LL] = sn;
                }
                float h = d[M - 1] * cs;
                d[M - 1] = h * oldcs;
                e[M - 2] = h * oldsn;
                for (int jj = 0; jj < M - LL; ++jj) {
                    float c = rc[jj], s = rs[jj];
                    if (c != 1.0f || s != 0.0f) {
                        int r0 = LL - 1 + jj;
                        for (int cc = 0; cc < 4; ++cc) {
                            float tmp = VT[r0 + 1][cc];
                            VT[r0 + 1][cc] = c * tmp - s * VT[r0][cc];
                            VT[r0][cc]     = s * tmp + c * VT[r0][cc];
                        }
                    }
                }
                if (fabsf(e[M - 2]) <= thresh) e[M - 2] = 0.0f;
            } else {
                float cs = 1.0f, oldcs = 1.0f, sn = 0.0f, oldsn = 0.0f, rr = 0.0f;
                for (int i = M; i >= LL + 1; --i) {
                    float fv = d[i - 1] * cs;
                    slartg_(fv, e[i - 2], cs, sn, rr);
                    if (i < M) e[i - 1] = oldsn * rr;
                    float fv2 = oldcs * rr;
                    float gv2 = d[i - 2] * sn;
                    slartg_(fv2, gv2, oldcs, oldsn, d[i - 1]);
                    rc[i - LL - 1] = oldcs; rs[i - LL - 1] = -oldsn;
                }
                float h = d[LL - 1] * cs;
                d[LL - 1] = h * oldcs;
                e[LL - 1] = h * oldsn;
                for (int jj = M - LL - 1; jj >= 0; --jj) {
                    float c = rc[jj], s = rs[jj];
                    if (c != 1.0f || s != 0.0f) {
                        int r0 = LL - 1 + jj;
                        for (int cc = 0; cc < 4; ++cc) {
                            float tmp = VT[r0 + 1][cc];
                            VT[r0 + 1][cc] = c * tmp - s * VT[r0][cc];
                            VT[r0][cc]     = s * tmp + c * VT[r0][cc];
                        }
                    }
                }
                if (fabsf(e[LL - 1]) <= thresh) e[LL - 1] = 0.0f;
            }
        } else {
            if (idir == 1) {
                float fv = (fabsf(d[LL - 1]) - shift) * (fsign(1.0f, d[LL - 1]) + shift / d[LL - 1]);
                float gv = e[LL - 1];
                float cosr, sinr, cosl, sinl, rr;
                for (int i = LL; i <= M - 1; ++i) {
                    slartg_(fv, gv, cosr, sinr, rr);
                    if (i > LL) e[i - 2] = rr;
                    fv = cosr * d[i - 1] + sinr * e[i - 1];
                    e[i - 1] = cosr * e[i - 1] - sinr * d[i - 1];
                    gv = sinr * d[i];
                    d[i] = cosr * d[i];
                    slartg_(fv, gv, cosl, sinl, rr);
                    d[i - 1] = rr;
                    fv = cosl * e[i - 1] + sinl * d[i];
                    d[i] = cosl * d[i] - sinl * e[i - 1];
                    if (i < M - 1) { gv = sinl * e[i]; e[i] = cosl * e[i]; }
                    rc[i - LL] = cosr; rs[i - LL] = sinr;
                }
                e[M - 2] = fv;
                for (int jj = 0; jj < M - LL; ++jj) {
                    float c = rc[jj], s = rs[jj];
                    if (c != 1.0f || s != 0.0f) {
                        int r0 = LL - 1 + jj;
                        for (int cc = 0; cc < 4; ++cc) {
                            float tmp = VT[r0 + 1][cc];
                            VT[r0 + 1][cc] = c * tmp - s * VT[r0][cc];
                            VT[r0][cc]     = s * tmp + c * VT[r0][cc];
                        }
                    }
                }
                if (fabsf(e[M - 2]) <= thresh) e[M - 2] = 0.0f;
            } else {
                float fv = (fabsf(d[M - 1]) - shift) * (fsign(1.0f, d[M - 1]) + shift / d[M - 1]);
                float gv = e[M - 2];
                float cosr, sinr, cosl, sinl, rr;
                for (int i = M; i >= LL + 1; --i) {
                    slartg_(fv, gv, cosr, sinr, rr);
                    if (i < M) e[i - 1] = rr;
                    fv = cosr * d[i - 1] + sinr * e[i - 2];
                    e[i - 2] = cosr * e[i - 2] - sinr * d[i - 1];
                    gv = sinr * d[i - 2];
                    d[i - 2] = cosr * d[i - 2];
                    slartg_(fv, gv, cosl, sinl, rr);
                    d[i - 1] = rr;
                    fv = cosl * e[i - 2] + sinl * d[i - 2];
                    d[i - 2] = cosl * d[i - 2] - sinl * e[i - 2];
                    if (i > LL + 1) { gv = sinl * e[i - 3]; e[i - 3] = cosl * e[i - 3]; }
                    rc[i - LL - 1] = cosl; rs[i - LL - 1] = -sinl;
                }
                e[LL - 1] = fv;
                if (fabsf(e[LL - 1]) <= thresh) e[LL - 1] = 0.0f;
                for (int jj = M - LL - 1; jj >= 0; --jj) {
                    float c = rc[jj], s = rs[jj];
                    if (c != 1.0f || s != 0.0f) {
                        int r0 = LL - 1 + jj;
                        for (int cc = 0; cc < 4; ++cc) {
                            float tmp = VT[r0 + 1][cc];
                            VT[r0 + 1][cc] = c * tmp - s * VT[r0][cc];
                            VT[r0][cc]     = s * tmp + c * VT[r0][cc];
                        }
                    }
                }
            }
        }
    }
    for (int i = 0; i < 4; ++i) {
        if (d[i] < 0.0f) {
            d[i] = -d[i];
            for (int cc = 0; cc < 4; ++cc) VT[i][cc] = -VT[i][cc];
        }
    }
    for (int i = 1; i <= 3; ++i) {
        int isub = 0; float smn = d[0];
        for (int jj = 1; jj <= 4 - i; ++jj)
            if (d[jj] <= smn) { isub = jj; smn = d[jj]; }
        int tgt = 4 - i;
        if (isub != tgt) {
            d[isub] = d[tgt]; d[tgt] = smn;
            for (int cc = 0; cc < 4; ++cc) {
                float t = VT[isub][cc]; VT[isub][cc] = VT[tgt][cc]; VT[tgt][cc] = t;
            }
        }
    }
}

// Build A (8x4) in f32 with numpy's exact op order; column-major Acm[col][row].
__device__ __forceinline__ void build_A(const float* __restrict__ points,
                                        const float* __restrict__ confs,
                                        const float* __restrict__ proj,
                                        int b, int j, float Acm[4][8]) {
    #pragma unroll
    for (int v = 0; v < VIEWS; ++v) {
        int bv = b * VIEWS + v;
        const float4* Pq = (const float4*)(proj + (size_t)bv * 12);
        float4 P0 = Pq[0];
        float4 P1 = Pq[1];
        float4 P2 = Pq[2];
        float2 pt = *(const float2*)(points + ((size_t)bv * JOINTS + j) * 2);
        float  cf = confs[(size_t)bv * JOINTS + j];
        float p2[4] = {P2.x, P2.y, P2.z, P2.w};
        float p0[4] = {P0.x, P0.y, P0.z, P0.w};
        float p1[4] = {P1.x, P1.y, P1.z, P1.w};
        #pragma unroll
        for (int cc = 0; cc < 4; ++cc) {
            float r0 = (p2[cc] * pt.x) - p0[cc];
            float r1 = (p2[cc] * pt.y) - p1[cc];
            Acm[cc][2 * v + 0] = r0 * cf;
            Acm[cc][2 * v + 1] = r1 * cf;
        }
    }
}

// Full sgesdd-f32 emulation for one (b,j) — byte-identical math to round 4.
__device__ void slow_solve(const float* __restrict__ points,
                           const float* __restrict__ confs,
                           const float* __restrict__ proj,
                           int b, int j, float& ox, float& oy, float& oz) {
    float Acm[4][8];
    build_A(points, confs, proj, b, j, Acm);

    // sgeqr2 (8x4)
    for (int jc = 0; jc < 4; ++jc) {
        float alpha = Acm[jc][jc];
        float tau = slarfg_(8 - jc, alpha, &Acm[jc][jc + 1]);
        if (tau != 0.0f) {
            for (int c = jc + 1; c < 4; ++c) {
                float w = Acm[c][jc];
                for (int r = jc + 1; r < 8; ++r) w = w + Acm[jc][r] * Acm[c][r];
                float temp = -tau * w;
                Acm[c][jc] = Acm[c][jc] + temp;
                for (int r = jc + 1; r < 8; ++r) Acm[c][r] = Acm[c][r] + Acm[jc][r] * temp;
            }
        }
        Acm[jc][jc] = alpha;
    }

    float Rg[4][4];
    #pragma unroll
    for (int c = 0; c < 4; ++c)
        #pragma unroll
        for (int r = 0; r < 4; ++r)
            Rg[c][r] = (r <= c) ? Acm[c][r] : 0.0f;

    // sgebd2 (4x4)
    float d_[4], e_[4], taup[4];
    for (int i = 0; i < 4; ++i) {
        float alpha = Rg[i][i];
        float tau = slarfg_(4 - i, alpha, &Rg[i][i + 1]);
        d_[i] = alpha;
        if (tau != 0.0f) {
            for (int c = i + 1; c < 4; ++c) {
                float w = Rg[c][i];
                for (int r = i + 1; r < 4; ++r) w = w + Rg[i][r] * Rg[c][r];
                float temp = -tau * w;
                Rg[c][i] = Rg[c][i] + temp;
                for (int r = i + 1; r < 4; ++r) Rg[c][r] = Rg[c][r] + Rg[i][r] * temp;
            }
        }
        if (i < 3) {
            float alpha2 = Rg[i + 1][i];
            float xb[2]; int nt = 2 - i;
            for (int t = 0; t < nt && t < 2; ++t) xb[t] = Rg[i + 2 + t][i];
            float tau2 = slarfg_(3 - i, alpha2, xb);
            e_[i] = alpha2;
            for (int t = 0; t < nt && t < 2; ++t) Rg[i + 2 + t][i] = xb[t];
            taup[i] = tau2;
            if (tau2 != 0.0f) {
                for (int r = i + 1; r < 4; ++r) {
                    float w = Rg[i + 1][r];
                    for (int c = i + 2; c < 4; ++c) w = w + Rg[c][i] * Rg[c][r];
                    float ntau = -tau2;
                    Rg[i + 1][r] = Rg[i + 1][r] + w * ntau;
                    for (int c = i + 2; c < 4; ++c) {
                        float tc = ntau * Rg[c][i];
                        Rg[c][r] = Rg[c][r] + w * tc;
                    }
                }
            }
        } else taup[i] = 0.0f;
    }

    float VT[4][4] = {{1,0,0,0},{0,1,0,0},{0,0,1,0},{0,0,0,1}};
    sbdsqr4_(d_, e_, VT);

    // sormbr('P','R','T') backward
    for (int ii = 2; ii >= 0; --ii) {
        float tau = taup[ii];
        if (tau == 0.0f) continue;
        for (int r = 0; r < 4; ++r) {
            float w = VT[r][ii + 1];
            for (int c = ii + 2; c < 4; ++c) w = w + VT[r][c] * Rg[c][ii];
            float ntau = -tau;
            VT[r][ii + 1] = VT[r][ii + 1] + w * ntau;
            for (int c = ii + 2; c < 4; ++c) {
                float tc = ntau * Rg[c][ii];
                VT[r][c] = VT[r][c] + w * tc;
            }
        }
    }

    float w3 = VT[3][3];
    ox = VT[3][0] / w3;
    oy = VT[3][1] / w3;
    oz = VT[3][2] / w3;
}

// ============================== kernel ==============================

__global__ __launch_bounds__(256) void triangulate_kernel(
    const float* __restrict__ points, const float* __restrict__ confs,
    const float* __restrict__ proj, float* __restrict__ out)
{
    int tid = blockIdx.x * blockDim.x + threadIdx.x;   // 0..HALF-1, grid exact
    int t0 = tid;
    int t1 = tid + HALF;

    // ---- build Gram matrices for both instances ----
    float M[2][4][4];   // upper triangle used
    float V[2][4][4];
    {
        float Acm[4][8];
        #pragma unroll
        for (int inst = 0; inst < 2; ++inst) {
            int tt = inst ? t1 : t0;
            int b = tt / JOINTS;
            int j = tt - b * JOINTS;
            build_A(points, confs, proj, b, j, Acm);
            #pragma unroll
            for (int c1 = 0; c1 < 4; ++c1)
                #pragma unroll
                for (int c2 = c1; c2 < 4; ++c2) {
                    float s = 0.0f;
                    #pragma unroll
                    for (int i = 0; i < 8; ++i)
                        s = fmaf(Acm[c1][i], Acm[c2][i], s);
                    M[inst][c1][c2] = s;
                }
            #pragma unroll
            for (int r = 0; r < 4; ++r)
                #pragma unroll
                for (int c = 0; c < 4; ++c)
                    V[inst][r][c] = (r == c) ? 1.0f : 0.0f;
        }
    }

    // ---- interleaved branchless two-sided Jacobi, 6 sweeps ----
    bool badconv[2] = {false, false};
    for (int sweep = 0; sweep < 6; ++sweep) {
        bool last = (sweep == 5);
        bool rot = false;
        #pragma unroll
        for (int p = 0; p < 3; ++p) {
            #pragma unroll
            for (int q = p + 1; q < 4; ++q) {
                #pragma unroll
                for (int inst = 0; inst < 2; ++inst) {
                    float lp = M[inst][p][p], lq = M[inst][q][q], g = M[inst][p][q];
                    bool cond = (g * g > 1e-14f * (lp * lq));
                    rot |= cond;
                    float gs = cond ? g : 1.0f;             // NaN/inf-safe divisor
                    float zeta = 0.5f * (lq - lp) * frcp(gs);
                    float t = fsign(frcp(fabsf(zeta) +
                                         fsqrtf(fmaf(zeta, zeta, 1.0f))), zeta);
                    t = cond ? t : 0.0f;                     // identity when skipped
                    badconv[inst] |= (last && fabsf(t) > 3e-4f);
                    float ci = frsq(fmaf(t, t, 1.0f));
                    float si = ci * t;
                    #pragma unroll
                    for (int k = 0; k < 4; ++k) {
                        if (k == p || k == q) continue;
                        float mpk = (k < p) ? M[inst][k][p] : M[inst][p][k];
                        float mqk = (k < q) ? M[inst][k][q] : M[inst][q][k];
                        float npk = fmaf(ci, mpk, -si * mqk);
                        float nqk = fmaf(si, mpk,  ci * mqk);
                        if (k < p) M[inst][k][p] = npk; else M[inst][p][k] = npk;
                        if (k < q) M[inst][k][q] = nqk; else M[inst][q][k] = nqk;
                    }
                    M[inst][p][p] = fmaf(-t, g, lp);
                    M[inst][q][q] = fmaf( t, g, lq);
                    M[inst][p][q] = cond ? 0.0f : g;
                    #pragma unroll
                    for (int i = 0; i < 4; ++i) {
                        float vp = V[inst][i][p], vq = V[inst][i][q];
                        V[inst][i][p] = fmaf(ci, vp, -si * vq);
                        V[inst][i][q] = fmaf(si, vp,  ci * vq);
                    }
                }
            }
        }
        if (!__any((int)rot)) break;
    }

    // ---- epilogue per instance: pick vector, est-flag, optional slow path ----
    #pragma unroll
    for (int inst = 0; inst < 2; ++inst) {
        float l0 = M[inst][0][0], l1 = M[inst][1][1];
        float l2 = M[inst][2][2], l3 = M[inst][3][3];
        int idx = 0; float lm = l0;
        if (l1 < lm) { lm = l1; idx = 1; }
        if (l2 < lm) { lm = l2; idx = 2; }
        if (l3 < lm) { lm = l3; idx = 3; }

        float a0 = l0, a1 = l1, a2 = l2, a3 = l3;
        { float t;
          if (a0 > a1) { t = a0; a0 = a1; a1 = t; }
          if (a2 > a3) { t = a2; a2 = a3; a3 = t; }
          if (a0 > a2) { t = a0; a0 = a2; a2 = t; }
          if (a1 > a3) { t = a1; a1 = a3; a3 = t; }
          if (a1 > a2) { t = a1; a1 = a2; a2 = t; }
        }
        float lgap = fmaxf(a1 - a0, 0.0f);   // <=0 -> frcp(0)=inf -> est=inf

        float hw  = V[inst][3][idx];
        float inv = frcp(hw);
        float ox = V[inst][0][idx] * inv;
        float oy = V[inst][1][idx] * inv;
        float oz = V[inst][2][idx] * inv;

        float osq = fmaf(ox, ox, fmaf(oy, oy, oz * oz));
        float est = EPS32 * (a3 * frcp(lgap)) * (1.0f + osq);
        bool flag = !(est <= 1000.0f) || badconv[inst];   // catches NaN/inf too

        int tt = inst ? t1 : t0;
        if (flag) {
            int b = tt / JOINTS;
            int j = tt - b * JOINTS;
            slow_solve(points, confs, proj, b, j, ox, oy, oz);
        }
        float* o = out + (size_t)tt * 3;
        o[0] = ox; o[1] = oy; o[2] = oz;
    }
}

extern "C" void kernel_launch(void* const* d_in, const int* in_sizes, int n_in,
                              void* d_out, int out_size, void* d_ws, size_t ws_size,
                              hipStream_t stream) {
    const float* points = (const float*)d_in[0];
    const float* confs  = (const float*)d_in[1];
    const float* proj   = (const float*)d_in[2];
    float* out = (float*)d_out;

    dim3 block(256);
    dim3 grid(HALF / 256);   // 2176, exact
    triangulate_kernel<<<grid, block, 0, stream>>>(points, confs, proj, out);
}